// Round 1
// baseline (804.899 us; speedup 1.0000x reference)
//
#include <hip/hip_runtime.h>

#define NUM_TAG 1024
#define TAG_DIM 128
#define NROWS   131072      // B*W = 128*1024
#define BM      64          // rows per block
#define BKC     32          // codebook chunk
#define TM      4           // rows per thread
#define TN      4           // cols per thread
#define P1_THREADS 128      // (BM/TM)*(BKC/TN) = 16*8

// -------- scc[k] = sum_d cb[k][d]^2 --------
__global__ void scc_kernel(const float* __restrict__ cb, float* __restrict__ scc) {
    int k = blockIdx.x * 256 + threadIdx.x;
    if (k >= NUM_TAG) return;
    const float4* row = reinterpret_cast<const float4*>(cb) + k * (TAG_DIM / 4);
    float s = 0.f;
#pragma unroll
    for (int i = 0; i < TAG_DIM / 4; ++i) {
        float4 v = row[i];
        s += v.x * v.x; s += v.y * v.y; s += v.z * v.z; s += v.w * v.w;
    }
    scc[k] = s;
}

// -------- phase 1: argmin over 1024 codes per row --------
// dist = (sxx[n] + scc[k]) - 2*dot  -- same op order as the np reference so
// rounding at magnitude ~128 (ulp 1.5e-5) quantizes ties the same way.
// Tie-break: lowest k (np.argmin semantics).
// LDS: XOR-swizzled float4 layout: element (row, c4) lives at [row][(c4 ^ (row&7))*4]
// -> inner-loop ds_read_b128 conflict-free (row&7 is wave-constant per operand group).
__global__ __launch_bounds__(P1_THREADS) void argmin_kernel(
    const float* __restrict__ x, const float* __restrict__ cb,
    const float* __restrict__ scc, int* __restrict__ idx_out,
    float* __restrict__ fidx_out)
{
    __shared__ float Xs[BM * TAG_DIM];    // 32 KB
    __shared__ float Cs[BKC * TAG_DIM];   // 16 KB
    __shared__ float sxx_s[BM];
    __shared__ float redv[BM][8];
    __shared__ int   redi[BM][8];

    const int tid = threadIdx.x;
    const int kx = tid & 7;     // col group 0..7
    const int ry = tid >> 3;    // row group 0..15
    const long row0 = (long)blockIdx.x * BM;

    // stage X tile: 2048 float4, 16 per thread, coalesced
    const float4* gx = reinterpret_cast<const float4*>(x) + row0 * (TAG_DIM / 4);
#pragma unroll
    for (int i = 0; i < 16; ++i) {
        int L = tid + i * P1_THREADS;
        int r = L >> 5, c4 = L & 31;
        *reinterpret_cast<float4*>(Xs + r * TAG_DIM + ((c4 ^ (r & 7)) << 2)) = gx[L];
    }
    __syncthreads();

    // per-row ||x||^2
    if (tid < BM) {
        float s = 0.f;
#pragma unroll
        for (int i = 0; i < 32; ++i) {
            float4 v = *reinterpret_cast<const float4*>(Xs + tid * TAG_DIM + ((i ^ (tid & 7)) << 2));
            s += v.x * v.x; s += v.y * v.y; s += v.z * v.z; s += v.w * v.w;
        }
        sxx_s[tid] = s;
    }

    float minv[TM]; int mini[TM];
#pragma unroll
    for (int r = 0; r < TM; ++r) { minv[r] = 3.4e38f; mini[r] = 0; }

    // swizzle offsets are wave-constant per operand: rows ry+16r -> &7 == ry&7; rows kx+8j -> &7 == kx
    const int sx = ry & 7;
    const int sc = kx;
    const float* Xrow = Xs + ry * TAG_DIM;   // +r*16*TAG_DIM folds to imm offsets
    const float* Crow = Cs + kx * TAG_DIM;   // +j*8*TAG_DIM folds to imm offsets

    for (int kc = 0; kc < NUM_TAG; kc += BKC) {
        __syncthreads();  // Cs reuse guard
        const float4* gc = reinterpret_cast<const float4*>(cb) + (long)kc * (TAG_DIM / 4);
#pragma unroll
        for (int i = 0; i < 8; ++i) {
            int L = tid + i * P1_THREADS;
            int r = L >> 5, c4 = L & 31;
            *reinterpret_cast<float4*>(Cs + r * TAG_DIM + ((c4 ^ (r & 7)) << 2)) = gc[L];
        }
        __syncthreads();

        float acc[TM][TN];
#pragma unroll
        for (int r = 0; r < TM; ++r)
#pragma unroll
            for (int j = 0; j < TN; ++j) acc[r][j] = 0.f;

#pragma unroll 8
        for (int d4 = 0; d4 < 32; ++d4) {
            const int ox = (d4 ^ sx) << 2;   // floats
            const int oc = (d4 ^ sc) << 2;
            float4 xa[TM], ca[TN];
#pragma unroll
            for (int r = 0; r < TM; ++r)
                xa[r] = *reinterpret_cast<const float4*>(Xrow + r * 16 * TAG_DIM + ox);
#pragma unroll
            for (int j = 0; j < TN; ++j)
                ca[j] = *reinterpret_cast<const float4*>(Crow + j * 8 * TAG_DIM + oc);
#pragma unroll
            for (int r = 0; r < TM; ++r)
#pragma unroll
                for (int j = 0; j < TN; ++j) {
                    acc[r][j] += xa[r].x * ca[j].x;
                    acc[r][j] += xa[r].y * ca[j].y;
                    acc[r][j] += xa[r].z * ca[j].z;
                    acc[r][j] += xa[r].w * ca[j].w;
                }
        }

        // fold chunk into running argmin (k ascending in-thread -> strict < keeps lowest k)
#pragma unroll
        for (int r = 0; r < TM; ++r) {
            float sxx = sxx_s[ry + r * 16];
#pragma unroll
            for (int j = 0; j < TN; ++j) {
                int k = kc + kx + j * 8;
                float s = sxx + scc[k];          // np: (sxx + scc)
                float dist = s - 2.0f * acc[r][j]; // np: ... - 2*dot
                if (dist < minv[r]) { minv[r] = dist; mini[r] = k; }
            }
        }
    }

#pragma unroll
    for (int r = 0; r < TM; ++r) { redv[ry + r * 16][kx] = minv[r]; redi[ry + r * 16][kx] = mini[r]; }
    __syncthreads();
    if (tid < BM) {
        float bv = redv[tid][0]; int bi = redi[tid][0];
#pragma unroll
        for (int e = 1; e < 8; ++e) {
            float v = redv[tid][e]; int ii = redi[tid][e];
            if (v < bv || (v == bv && ii < bi)) { bv = v; bi = ii; }  // tie -> lowest k
        }
        idx_out[row0 + tid] = bi;
        fidx_out[row0 + tid] = (float)bi;
    }
}

// -------- phase 2: gather + STE output + loss partials --------
__global__ __launch_bounds__(256) void quant_kernel(
    const float* __restrict__ x, const float* __restrict__ cb,
    const int* __restrict__ idx, float* __restrict__ out,
    double* __restrict__ partial)
{
    const int N4 = NROWS * (TAG_DIM / 4);  // 4,194,304 float4
    double s = 0.0;
    for (int i = blockIdx.x * blockDim.x + threadIdx.x; i < N4; i += gridDim.x * blockDim.x) {
        int n = i >> 5;        // row
        int d4 = i & 31;
        int k = idx[n];
        float4 xv = reinterpret_cast<const float4*>(x)[i];
        float4 qv = reinterpret_cast<const float4*>(cb)[k * 32 + d4];
        float dx = qv.x - xv.x, dy = qv.y - xv.y, dz = qv.z - xv.z, dw = qv.w - xv.w;
        float4 o;  // STE: x + (q - x), same op order as reference
        o.x = xv.x + dx; o.y = xv.y + dy; o.z = xv.z + dz; o.w = xv.w + dw;
        reinterpret_cast<float4*>(out)[i] = o;
        s += (double)dx * dx; s += (double)dy * dy; s += (double)dz * dz; s += (double)dw * dw;
    }
    __shared__ double sd[256];
    sd[threadIdx.x] = s;
    __syncthreads();
    for (int off = 128; off > 0; off >>= 1) {
        if (threadIdx.x < (unsigned)off) sd[threadIdx.x] += sd[threadIdx.x + off];
        __syncthreads();
    }
    if (threadIdx.x == 0) partial[blockIdx.x] = sd[0];
}

__global__ __launch_bounds__(256) void loss_kernel(
    const double* __restrict__ partial, int n, float* __restrict__ out_loss)
{
    __shared__ double sd[256];
    double s = 0.0;
    for (int i = threadIdx.x; i < n; i += 256) s += partial[i];
    sd[threadIdx.x] = s;
    __syncthreads();
    for (int off = 128; off > 0; off >>= 1) {
        if (threadIdx.x < (unsigned)off) sd[threadIdx.x] += sd[threadIdx.x + off];
        __syncthreads();
    }
    if (threadIdx.x == 0) {
        double mean = sd[0] / (double)((long long)NROWS * TAG_DIM);
        out_loss[0] = (float)(mean + 0.25 * mean);   // q_latent + 0.25*e_latent
    }
}

extern "C" void kernel_launch(void* const* d_in, const int* in_sizes, int n_in,
                              void* d_out, int out_size, void* d_ws, size_t ws_size,
                              hipStream_t stream) {
    const float* x  = (const float*)d_in[0];   // [131072][128]
    const float* cb = (const float*)d_in[1];   // [1024][128]
    float* out      = (float*)d_out;
    float* out_loss = out + (long)NROWS * TAG_DIM;   // element 16777216
    float* out_fidx = out_loss + 1;                  // 131072 indices as f32

    // ws: scc[1024] f32 | idx[131072] i32 | partial[2048] f64  (~545 KB)
    float*  scc     = (float*)d_ws;
    int*    idxb    = (int*)((char*)d_ws + 4096);
    double* partial = (double*)((char*)d_ws + 4096 + (size_t)NROWS * 4);

    scc_kernel   <<<4, 256, 0, stream>>>(cb, scc);
    argmin_kernel<<<NROWS / BM, P1_THREADS, 0, stream>>>(x, cb, scc, idxb, out_fidx);
    quant_kernel <<<2048, 256, 0, stream>>>(x, cb, idxb, out, partial);
    loss_kernel  <<<1, 256, 0, stream>>>(partial, 2048, out_loss);
}

// Round 3
// 588.037 us; speedup vs baseline: 1.3688x; 1.3688x over previous
//
#include <hip/hip_runtime.h>

#define NUM_TAG 1024
#define TAG_DIM 128
#define NROWS   131072      // B*W = 128*1024
#define FLAG_M  1.25e-4f    // flag margin: >> 2*delta + np rounding windows

typedef __attribute__((ext_vector_type(8))) short short8;
typedef __attribute__((ext_vector_type(4))) float f32x4;

// Exact 2-way bf16 split: x = h + m + (residual < 2^-16 |x|), h/m bf16-exact.
__device__ inline void split2(float xv, unsigned short& h, unsigned short& m) {
    unsigned xb = __float_as_uint(xv);
    unsigned hb = xb & 0xFFFF0000u;
    float r1 = xv - __uint_as_float(hb);        // Sterbenz-exact
    unsigned mb = __float_as_uint(r1) & 0xFFFF0000u;
    h = (unsigned short)(hb >> 16);
    m = (unsigned short)(mb >> 16);
}

// -------- prep: scc[k] = ||cb_k||^2 (round-1 sequential order) + h/m split --------
__global__ __launch_bounds__(256) void prep_cb_kernel(
    const float* __restrict__ cb, float* __restrict__ scc,
    unsigned short* __restrict__ cbh, unsigned short* __restrict__ cbm)
{
    int k = blockIdx.x * 256 + threadIdx.x;
    if (k >= NUM_TAG) return;
    const float4* row = reinterpret_cast<const float4*>(cb) + k * (TAG_DIM / 4);
    float s = 0.f;
#pragma unroll
    for (int i = 0; i < TAG_DIM / 4; ++i) {
        float4 v = row[i];
        s += v.x * v.x; s += v.y * v.y; s += v.z * v.z; s += v.w * v.w;
        ushort4 h, m;
        split2(v.x, h.x, m.x);
        split2(v.y, h.y, m.y);
        split2(v.z, h.z, m.z);
        split2(v.w, h.w, m.w);
        reinterpret_cast<ushort4*>(cbh)[k * 32 + i] = h;
        reinterpret_cast<ushort4*>(cbm)[k * 32 + i] = m;
    }
    scc[k] = s;
}

// -------- pass A: split-bf16 MFMA scores + top-2 + near-tie flagging --------
// score_k = scc_k - 2*dot (sxx is row-constant -> cancels in argmin/gap).
// 512 threads = 8 waves, 256 rows/block (32/wave). A-frags live in VGPRs.
__global__ __launch_bounds__(512, 2) void argmin_mfma_kernel(
    const float* __restrict__ x,
    const unsigned short* __restrict__ cbh, const unsigned short* __restrict__ cbm,
    const float* __restrict__ scc,
    float* __restrict__ fidx_out, int* __restrict__ flag_out)
{
    const int tid = threadIdx.x;
    const int w   = tid >> 6;
    const int l   = tid & 63;
    const int l15 = l & 15;
    const int l4  = l >> 4;
    const int row0 = blockIdx.x * 256 + w * 32;

    // A fragments: lane holds row l15 (+16*rf), k-slice l4*8+e of K-step s
    short8 Ah[2][4], Am[2][4];
#pragma unroll
    for (int rf = 0; rf < 2; ++rf) {
        const float4* xp = reinterpret_cast<const float4*>(x) +
                           (long)(row0 + rf * 16 + l15) * 32 + l4 * 2;
#pragma unroll
        for (int s = 0; s < 4; ++s) {
            float4 v0 = xp[s * 8];
            float4 v1 = xp[s * 8 + 1];
            float xv[8] = {v0.x, v0.y, v0.z, v0.w, v1.x, v1.y, v1.z, v1.w};
#pragma unroll
            for (int e = 0; e < 8; ++e) {
                unsigned short h, m;
                split2(xv[e], h, m);
                Ah[rf][s][e] = (short)h;
                Am[rf][s][e] = (short)m;
            }
        }
    }

    float m1[2][4], m2[2][4]; int i1[2][4];
#pragma unroll
    for (int rf = 0; rf < 2; ++rf)
#pragma unroll
        for (int r = 0; r < 4; ++r) { m1[rf][r] = 3.4e38f; m2[rf][r] = 3.4e38f; i1[rf][r] = 0; }

    for (int ch = 0; ch < 16; ++ch) {
        const int col0 = ch << 6;
        f32x4 acc[2][4];
#pragma unroll
        for (int rf = 0; rf < 2; ++rf)
#pragma unroll
            for (int c = 0; c < 4; ++c) acc[rf][c] = (f32x4)0.f;

#pragma unroll
        for (int s = 0; s < 4; ++s) {
            short8 Bh[4], Bm[4];
#pragma unroll
            for (int c = 0; c < 4; ++c) {
                int off = ((col0 + c * 16 + l15) << 7) + (s << 5) + (l4 << 3);
                Bh[c] = *reinterpret_cast<const short8*>(cbh + off);
                Bm[c] = *reinterpret_cast<const short8*>(cbm + off);
            }
#pragma unroll
            for (int c = 0; c < 4; ++c)
#pragma unroll
                for (int rf = 0; rf < 2; ++rf) {
                    acc[rf][c] = __builtin_amdgcn_mfma_f32_16x16x32_bf16(Ah[rf][s], Bm[c], acc[rf][c], 0, 0, 0);
                    acc[rf][c] = __builtin_amdgcn_mfma_f32_16x16x32_bf16(Am[rf][s], Bh[c], acc[rf][c], 0, 0, 0);
                    acc[rf][c] = __builtin_amdgcn_mfma_f32_16x16x32_bf16(Ah[rf][s], Bh[c], acc[rf][c], 0, 0, 0);
                }
        }

        // fold into running top-2 per output row
#pragma unroll
        for (int c = 0; c < 4; ++c) {
            const int k = col0 + c * 16 + l15;
            const float sccv = scc[k];
#pragma unroll
            for (int rf = 0; rf < 2; ++rf)
#pragma unroll
                for (int r = 0; r < 4; ++r) {
                    float score = sccv - 2.0f * acc[rf][c][r];
                    if (score < m1[rf][r]) {
                        m2[rf][r] = m1[rf][r]; m1[rf][r] = score; i1[rf][r] = k;
                    } else if (score < m2[rf][r]) {
                        m2[rf][r] = score;
                    }
                }
        }
    }

    // cross-lane top-2 merge within each 16-lane col group
#pragma unroll
    for (int rf = 0; rf < 2; ++rf)
#pragma unroll
        for (int r = 0; r < 4; ++r) {
            float v1 = m1[rf][r], v2 = m2[rf][r]; int ii = i1[rf][r];
#pragma unroll
            for (int mk = 1; mk < 16; mk <<= 1) {
                float o1 = __shfl_xor(v1, mk, 64);
                float o2 = __shfl_xor(v2, mk, 64);
                int   oi = __shfl_xor(ii, mk, 64);
                float n2 = fminf(fminf(v2, o2), fmaxf(v1, o1));  // global 2nd-min
                if (o1 < v1 || (o1 == v1 && oi < ii)) { v1 = o1; ii = oi; }
                v2 = n2;
            }
            if (l15 == 0) {
                int row = row0 + rf * 16 + l4 * 4 + r;
                fidx_out[row] = (float)ii;
                flag_out[row] = (v2 - v1 <= FLAG_M) ? 1 : 0;
            }
        }
}

// -------- pass B: exact rescore of flagged rows (round-1 bit-exact recipe) --------
__global__ __launch_bounds__(256) void exact_fix_kernel(
    const float* __restrict__ x, const float* __restrict__ cb,
    const float* __restrict__ scc, const int* __restrict__ flag,
    float* __restrict__ fidx_out)
{
    __shared__ float Xs[TAG_DIM];
    __shared__ float sxxs;
    __shared__ float rv[256];
    __shared__ int   ri[256];
    __shared__ unsigned long long smask;

    const int tid = threadIdx.x;
    const int base = blockIdx.x * 64;

    if (tid < 64) {
        unsigned long long mask = __ballot(flag[base + tid] != 0);
        if (tid == 0) smask = mask;
    }
    __syncthreads();
    unsigned long long mm = smask;

    while (mm) {
        int rbit = __builtin_ctzll(mm); mm &= mm - 1;
        const long n = base + rbit;

        if (tid < 32)
            reinterpret_cast<float4*>(Xs)[tid] =
                reinterpret_cast<const float4*>(x)[n * 32 + tid];
        __syncthreads();
        if (tid == 0) {
            float s = 0.f;
            for (int i = 0; i < 32; ++i) {   // sequential: round-1 sxx order
                float4 v = reinterpret_cast<float4*>(Xs)[i];
                s += v.x * v.x; s += v.y * v.y; s += v.z * v.z; s += v.w * v.w;
            }
            sxxs = s;
        }
        __syncthreads();
        const float sxxv = sxxs;

        float bv = 3.4e38f; int bi = 0;
#pragma unroll
        for (int j = 0; j < 4; ++j) {
            int k = tid * 4 + j;             // in-thread ascending k
            const float4* crow = reinterpret_cast<const float4*>(cb) + k * 32;
            float acc = 0.f;
            for (int i = 0; i < 32; ++i) {   // sequential fp32 fmac: round-1 dot order
                float4 c = crow[i];
                float4 v = reinterpret_cast<float4*>(Xs)[i];
                acc += v.x * c.x; acc += v.y * c.y; acc += v.z * c.z; acc += v.w * c.w;
            }
            float s1 = sxxv + scc[k];        // np: (sxx + scc)
            float dist = s1 - 2.0f * acc;    // np: ... - 2*dot
            if (dist < bv) { bv = dist; bi = k; }
        }
        rv[tid] = bv; ri[tid] = bi;
        __syncthreads();
        for (int off = 128; off > 0; off >>= 1) {
            if (tid < off) {
                float v = rv[tid + off]; int oi = ri[tid + off];
                if (v < rv[tid] || (v == rv[tid] && oi < ri[tid])) { rv[tid] = v; ri[tid] = oi; }
            }
            __syncthreads();
        }
        if (tid == 0) fidx_out[n] = (float)ri[0];
        __syncthreads();
    }
}

// -------- phase 2: gather + STE output + loss partials --------
__global__ __launch_bounds__(256) void quant_kernel(
    const float* __restrict__ x, const float* __restrict__ cb,
    const float* __restrict__ fidx, float* __restrict__ out,
    double* __restrict__ partial)
{
    const int N4 = NROWS * (TAG_DIM / 4);
    double s = 0.0;
    for (int i = blockIdx.x * blockDim.x + threadIdx.x; i < N4; i += gridDim.x * blockDim.x) {
        int n = i >> 5;
        int d4 = i & 31;
        int k = (int)fidx[n];
        float4 xv = reinterpret_cast<const float4*>(x)[i];
        float4 qv = reinterpret_cast<const float4*>(cb)[k * 32 + d4];
        float dx = qv.x - xv.x, dy = qv.y - xv.y, dz = qv.z - xv.z, dw = qv.w - xv.w;
        float4 o;
        o.x = xv.x + dx; o.y = xv.y + dy; o.z = xv.z + dz; o.w = xv.w + dw;
        reinterpret_cast<float4*>(out)[i] = o;
        s += (double)dx * dx; s += (double)dy * dy; s += (double)dz * dz; s += (double)dw * dw;
    }
    __shared__ double sd[256];
    sd[threadIdx.x] = s;
    __syncthreads();
    for (int off = 128; off > 0; off >>= 1) {
        if (threadIdx.x < (unsigned)off) sd[threadIdx.x] += sd[threadIdx.x + off];
        __syncthreads();
    }
    if (threadIdx.x == 0) partial[blockIdx.x] = sd[0];
}

__global__ __launch_bounds__(256) void loss_kernel(
    const double* __restrict__ partial, int n, float* __restrict__ out_loss)
{
    __shared__ double sd[256];
    double s = 0.0;
    for (int i = threadIdx.x; i < n; i += 256) s += partial[i];
    sd[threadIdx.x] = s;
    __syncthreads();
    for (int off = 128; off > 0; off >>= 1) {
        if (threadIdx.x < (unsigned)off) sd[threadIdx.x] += sd[threadIdx.x + off];
        __syncthreads();
    }
    if (threadIdx.x == 0) {
        double mean = sd[0] / (double)((long long)NROWS * TAG_DIM);
        out_loss[0] = (float)(mean + 0.25 * mean);
    }
}

extern "C" void kernel_launch(void* const* d_in, const int* in_sizes, int n_in,
                              void* d_out, int out_size, void* d_ws, size_t ws_size,
                              hipStream_t stream) {
    const float* x  = (const float*)d_in[0];   // [131072][128]
    const float* cb = (const float*)d_in[1];   // [1024][128]
    float* out      = (float*)d_out;
    float* out_loss = out + (long)NROWS * TAG_DIM;
    float* out_fidx = out_loss + 1;            // 131072 indices as f32

    // ws layout (~1.05 MB): scc | cbh | cbm | flags | partial
    char* wsb = (char*)d_ws;
    float*          scc     = (float*)(wsb);                     // 4 KB
    unsigned short* cbh     = (unsigned short*)(wsb + 4096);     // 256 KB
    unsigned short* cbm     = (unsigned short*)(wsb + 266240);   // 256 KB
    int*            flags   = (int*)(wsb + 528384);              // 512 KB
    double*         partial = (double*)(wsb + 1052672);          // 16 KB

    prep_cb_kernel    <<<4, 256, 0, stream>>>(cb, scc, cbh, cbm);
    argmin_mfma_kernel<<<NROWS / 256, 512, 0, stream>>>(x, cbh, cbm, scc, out_fidx, flags);
    exact_fix_kernel  <<<NROWS / 64, 256, 0, stream>>>(x, cb, scc, flags, out_fidx);
    quant_kernel      <<<2048, 256, 0, stream>>>(x, cb, out_fidx, out, partial);
    loss_kernel       <<<1, 256, 0, stream>>>(partial, 2048, out_loss);
}

// Round 5
// 443.858 us; speedup vs baseline: 1.8134x; 1.3248x over previous
//
#include <hip/hip_runtime.h>

#define NUM_TAG 1024
#define TAG_DIM 128
#define NROWS   131072      // B*W = 128*1024
#define FLAG_M  1.25e-4f    // flag margin: >> 2*delta + np rounding windows

typedef __attribute__((ext_vector_type(8))) short short8;
typedef __attribute__((ext_vector_type(4))) float f32x4;

// Exact 2-way bf16 split: x = h + m + (residual < 2^-16 |x|), h/m bf16-exact.
__device__ inline void split2(float xv, unsigned short& h, unsigned short& m) {
    unsigned xb = __float_as_uint(xv);
    unsigned hb = xb & 0xFFFF0000u;
    float r1 = xv - __uint_as_float(hb);        // Sterbenz-exact
    unsigned mb = __float_as_uint(r1) & 0xFFFF0000u;
    h = (unsigned short)(hb >> 16);
    m = (unsigned short)(mb >> 16);
}

// -------- scc[k] = ||cb_k||^2 (round-1 sequential order, bit-identical) --------
__global__ __launch_bounds__(256) void prep_scc_kernel(
    const float* __restrict__ cb, float* __restrict__ scc)
{
    int k = blockIdx.x * 256 + threadIdx.x;
    if (k >= NUM_TAG) return;
    const float4* row = reinterpret_cast<const float4*>(cb) + k * (TAG_DIM / 4);
    float s = 0.f;
#pragma unroll
    for (int i = 0; i < TAG_DIM / 4; ++i) {
        float4 v = row[i];
        s += v.x * v.x; s += v.y * v.y; s += v.z * v.z; s += v.w * v.w;
    }
    scc[k] = s;
}

// -------- split codebook in MFMA-B-fragment-linear order --------
// Chunk = 64 codes: 2 arrays (h,m) x 16 (s,c) x 64 lanes x 8 elems
//       = 16384 ushorts = 32 KB.  (Round-4 bug: stride was 32768 = bytes.)
// cbf[ch*16384 + ((arr*16 + s*4 + c)*64 + l)*8 + e]
//   = split(cb[ch*64 + c*16 + (l&15)][s*32 + (l>>4)*8 + e])
__global__ __launch_bounds__(256) void prep_frag_kernel(
    const float* __restrict__ cb, unsigned short* __restrict__ cbf)
{
    int t = blockIdx.x * 256 + threadIdx.x;
    int l  = t & 63;
    int c  = (t >> 6) & 3;
    int s  = (t >> 8) & 3;
    int ch = t >> 10;
    int k  = ch * 64 + c * 16 + (l & 15);
    int d0 = s * 32 + (l >> 4) * 8;
    const float4* xp = reinterpret_cast<const float4*>(cb) + k * 32 + (d0 >> 2);
    float4 v0 = xp[0], v1 = xp[1];
    float xv[8] = {v0.x, v0.y, v0.z, v0.w, v1.x, v1.y, v1.z, v1.w};
    short8 hh, mm;
#pragma unroll
    for (int e = 0; e < 8; ++e) {
        unsigned short h, m;
        split2(xv[e], h, m);
        hh[e] = (short)h; mm[e] = (short)m;
    }
    long baseh = (long)ch * 16384 + ((0 * 16 + s * 4 + c) * 64 + l) * 8;
    long basem = (long)ch * 16384 + ((1 * 16 + s * 4 + c) * 64 + l) * 8;
    *reinterpret_cast<short8*>(cbf + baseh) = hh;
    *reinterpret_cast<short8*>(cbf + basem) = mm;
}

// -------- pass A: split-bf16 MFMA scores + top-2 + near-tie flagging --------
// B streamed via LDS double buffer (each block reads the 512 KB frag codebook
// once; 8 waves share). Scores bit-identical to round 3.
__global__ __launch_bounds__(512, 2) void argmin_mfma_kernel(
    const float* __restrict__ x,
    const unsigned short* __restrict__ cbf,
    const float* __restrict__ scc,
    float* __restrict__ fidx_out, int* __restrict__ flag_out)
{
    __shared__ __align__(16) unsigned short lds[2][16384];   // 2 x 32 KB

    const int tid = threadIdx.x;
    const int w   = tid >> 6;
    const int l   = tid & 63;
    const int l15 = l & 15;
    const int l4  = l >> 4;
    const int row0 = blockIdx.x * 256 + w * 32;

    // ---- A fragments: lane holds row l15 (+16*rf), k-slice l4*8+e, step s ----
    short8 Ah[2][4], Am[2][4];
#pragma unroll
    for (int rf = 0; rf < 2; ++rf) {
        const float4* xp = reinterpret_cast<const float4*>(x) +
                           (long)(row0 + rf * 16 + l15) * 32 + l4 * 2;
#pragma unroll
        for (int s = 0; s < 4; ++s) {
            float4 v0 = xp[s * 8];
            float4 v1 = xp[s * 8 + 1];
            float xv[8] = {v0.x, v0.y, v0.z, v0.w, v1.x, v1.y, v1.z, v1.w};
#pragma unroll
            for (int e = 0; e < 8; ++e) {
                unsigned short h, m;
                split2(xv[e], h, m);
                Ah[rf][s][e] = (short)h;
                Am[rf][s][e] = (short)m;
            }
        }
    }

    float m1[2][4], m2[2][4]; int i1[2][4];
#pragma unroll
    for (int rf = 0; rf < 2; ++rf)
#pragma unroll
        for (int r = 0; r < 4; ++r) { m1[rf][r] = 3.4e38f; m2[rf][r] = 3.4e38f; i1[rf][r] = 0; }

    const float4* gsrc = reinterpret_cast<const float4*>(cbf);  // chunk = 2048 float4

    // ---- prologue: stage chunk 0 ----
    {
        float4 st[4];
#pragma unroll
        for (int i = 0; i < 4; ++i) st[i] = gsrc[i * 512 + tid];
#pragma unroll
        for (int i = 0; i < 4; ++i)
            reinterpret_cast<float4*>(&lds[0][0])[i * 512 + tid] = st[i];
    }
    __syncthreads();

    for (int ch = 0; ch < 16; ++ch) {
        const int b = ch & 1;
        // issue next-chunk global loads early (latency hides under MFMA)
        float4 st[4];
        if (ch < 15) {
#pragma unroll
            for (int i = 0; i < 4; ++i)
                st[i] = gsrc[(ch + 1) * 2048 + i * 512 + tid];
        }

        const int col0 = ch << 6;
        f32x4 acc[2][4];
#pragma unroll
        for (int rf = 0; rf < 2; ++rf)
#pragma unroll
            for (int c = 0; c < 4; ++c) acc[rf][c] = (f32x4)0.f;

#pragma unroll
        for (int s = 0; s < 4; ++s) {
#pragma unroll
            for (int c = 0; c < 4; ++c) {
                const short8 Bh = *reinterpret_cast<const short8*>(
                    &lds[b][((0 * 16 + s * 4 + c) * 64 + l) * 8]);
                const short8 Bm = *reinterpret_cast<const short8*>(
                    &lds[b][((1 * 16 + s * 4 + c) * 64 + l) * 8]);
#pragma unroll
                for (int rf = 0; rf < 2; ++rf) {
                    acc[rf][c] = __builtin_amdgcn_mfma_f32_16x16x32_bf16(Ah[rf][s], Bm, acc[rf][c], 0, 0, 0);
                    acc[rf][c] = __builtin_amdgcn_mfma_f32_16x16x32_bf16(Am[rf][s], Bh, acc[rf][c], 0, 0, 0);
                    acc[rf][c] = __builtin_amdgcn_mfma_f32_16x16x32_bf16(Ah[rf][s], Bh, acc[rf][c], 0, 0, 0);
                }
            }
        }

        // fold into running top-2 per output row (identical to round 3)
#pragma unroll
        for (int c = 0; c < 4; ++c) {
            const int k = col0 + c * 16 + l15;
            const float sccv = scc[k];
#pragma unroll
            for (int rf = 0; rf < 2; ++rf)
#pragma unroll
                for (int r = 0; r < 4; ++r) {
                    float score = sccv - 2.0f * acc[rf][c][r];
                    if (score < m1[rf][r]) {
                        m2[rf][r] = m1[rf][r]; m1[rf][r] = score; i1[rf][r] = k;
                    } else if (score < m2[rf][r]) {
                        m2[rf][r] = score;
                    }
                }
        }

        __syncthreads();   // all waves done reading lds[b^1] (from iter ch-1)
        if (ch < 15) {
#pragma unroll
            for (int i = 0; i < 4; ++i)
                reinterpret_cast<float4*>(&lds[b ^ 1][0])[i * 512 + tid] = st[i];
        }
        __syncthreads();   // staged chunk visible before compute(ch+1)
    }

    // ---- cross-lane top-2 merge within each 16-lane col group ----
#pragma unroll
    for (int rf = 0; rf < 2; ++rf)
#pragma unroll
        for (int r = 0; r < 4; ++r) {
            float v1 = m1[rf][r], v2 = m2[rf][r]; int ii = i1[rf][r];
#pragma unroll
            for (int mk = 1; mk < 16; mk <<= 1) {
                float o1 = __shfl_xor(v1, mk, 64);
                float o2 = __shfl_xor(v2, mk, 64);
                int   oi = __shfl_xor(ii, mk, 64);
                float n2 = fminf(fminf(v2, o2), fmaxf(v1, o1));  // global 2nd-min
                if (o1 < v1 || (o1 == v1 && oi < ii)) { v1 = o1; ii = oi; }
                v2 = n2;
            }
            if (l15 == 0) {
                int row = row0 + rf * 16 + l4 * 4 + r;
                fidx_out[row] = (float)ii;
                flag_out[row] = (v2 - v1 <= FLAG_M) ? 1 : 0;
            }
        }
}

// -------- pass B: exact rescore of flagged rows (round-1 bit-exact recipe) --------
__global__ __launch_bounds__(256) void exact_fix_kernel(
    const float* __restrict__ x, const float* __restrict__ cb,
    const float* __restrict__ scc, const int* __restrict__ flag,
    float* __restrict__ fidx_out)
{
    __shared__ float Xs[TAG_DIM];
    __shared__ float sxxs;
    __shared__ float rv[256];
    __shared__ int   ri[256];
    __shared__ unsigned long long smask;

    const int tid = threadIdx.x;
    const int base = blockIdx.x * 64;

    if (tid < 64) {
        unsigned long long mask = __ballot(flag[base + tid] != 0);
        if (tid == 0) smask = mask;
    }
    __syncthreads();
    unsigned long long mm = smask;

    while (mm) {
        int rbit = __builtin_ctzll(mm); mm &= mm - 1;
        const long n = base + rbit;

        if (tid < 32)
            reinterpret_cast<float4*>(Xs)[tid] =
                reinterpret_cast<const float4*>(x)[n * 32 + tid];
        __syncthreads();
        if (tid == 0) {
            float s = 0.f;
            for (int i = 0; i < 32; ++i) {   // sequential: round-1 sxx order
                float4 v = reinterpret_cast<float4*>(Xs)[i];
                s += v.x * v.x; s += v.y * v.y; s += v.z * v.z; s += v.w * v.w;
            }
            sxxs = s;
        }
        __syncthreads();
        const float sxxv = sxxs;

        float bv = 3.4e38f; int bi = 0;
#pragma unroll
        for (int j = 0; j < 4; ++j) {
            int k = tid * 4 + j;             // in-thread ascending k
            const float4* crow = reinterpret_cast<const float4*>(cb) + k * 32;
            float acc = 0.f;
            for (int i = 0; i < 32; ++i) {   // sequential fp32 fmac: round-1 dot order
                float4 c = crow[i];
                float4 v = reinterpret_cast<float4*>(Xs)[i];
                acc += v.x * c.x; acc += v.y * c.y; acc += v.z * c.z; acc += v.w * c.w;
            }
            float s1 = sxxv + scc[k];        // np: (sxx + scc)
            float dist = s1 - 2.0f * acc;    // np: ... - 2*dot
            if (dist < bv) { bv = dist; bi = k; }
        }
        rv[tid] = bv; ri[tid] = bi;
        __syncthreads();
        for (int off = 128; off > 0; off >>= 1) {
            if (tid < off) {
                float v = rv[tid + off]; int oi = ri[tid + off];
                if (v < rv[tid] || (v == rv[tid] && oi < ri[tid])) { rv[tid] = v; ri[tid] = oi; }
            }
            __syncthreads();
        }
        if (tid == 0) fidx_out[n] = (float)ri[0];
        __syncthreads();
    }
}

// -------- phase 2: gather + STE output + loss partials --------
__global__ __launch_bounds__(256) void quant_kernel(
    const float* __restrict__ x, const float* __restrict__ cb,
    const float* __restrict__ fidx, float* __restrict__ out,
    double* __restrict__ partial)
{
    const int N4 = NROWS * (TAG_DIM / 4);
    double s = 0.0;
    for (int i = blockIdx.x * blockDim.x + threadIdx.x; i < N4; i += gridDim.x * blockDim.x) {
        int n = i >> 5;
        int d4 = i & 31;
        int k = (int)fidx[n];
        float4 xv = reinterpret_cast<const float4*>(x)[i];
        float4 qv = reinterpret_cast<const float4*>(cb)[k * 32 + d4];
        float dx = qv.x - xv.x, dy = qv.y - xv.y, dz = qv.z - xv.z, dw = qv.w - xv.w;
        float4 o;
        o.x = xv.x + dx; o.y = xv.y + dy; o.z = xv.z + dz; o.w = xv.w + dw;
        reinterpret_cast<float4*>(out)[i] = o;
        s += (double)dx * dx; s += (double)dy * dy; s += (double)dz * dz; s += (double)dw * dw;
    }
    __shared__ double sd[256];
    sd[threadIdx.x] = s;
    __syncthreads();
    for (int off = 128; off > 0; off >>= 1) {
        if (threadIdx.x < (unsigned)off) sd[threadIdx.x] += sd[threadIdx.x + off];
        __syncthreads();
    }
    if (threadIdx.x == 0) partial[blockIdx.x] = sd[0];
}

__global__ __launch_bounds__(256) void loss_kernel(
    const double* __restrict__ partial, int n, float* __restrict__ out_loss)
{
    __shared__ double sd[256];
    double s = 0.0;
    for (int i = threadIdx.x; i < n; i += 256) s += partial[i];
    sd[threadIdx.x] = s;
    __syncthreads();
    for (int off = 128; off > 0; off >>= 1) {
        if (threadIdx.x < (unsigned)off) sd[threadIdx.x] += sd[threadIdx.x + off];
        __syncthreads();
    }
    if (threadIdx.x == 0) {
        double mean = sd[0] / (double)((long long)NROWS * TAG_DIM);
        out_loss[0] = (float)(mean + 0.25 * mean);
    }
}

extern "C" void kernel_launch(void* const* d_in, const int* in_sizes, int n_in,
                              void* d_out, int out_size, void* d_ws, size_t ws_size,
                              hipStream_t stream) {
    const float* x  = (const float*)d_in[0];   // [131072][128]
    const float* cb = (const float*)d_in[1];   // [1024][128]
    float* out      = (float*)d_out;
    float* out_loss = out + (long)NROWS * TAG_DIM;
    float* out_fidx = out_loss + 1;            // 131072 indices as f32

    // ws layout (~1.05 MB): scc | cbf (frag-linear h+m) | flags | partial
    char* wsb = (char*)d_ws;
    float*          scc     = (float*)(wsb);                     // 4 KB
    unsigned short* cbf     = (unsigned short*)(wsb + 4096);     // 512 KB
    int*            flags   = (int*)(wsb + 528384);              // 512 KB
    double*         partial = (double*)(wsb + 1052672);          // 16 KB

    prep_scc_kernel   <<<4, 256, 0, stream>>>(cb, scc);
    prep_frag_kernel  <<<64, 256, 0, stream>>>(cb, cbf);
    argmin_mfma_kernel<<<NROWS / 256, 512, 0, stream>>>(x, cbf, scc, out_fidx, flags);
    exact_fix_kernel  <<<NROWS / 64, 256, 0, stream>>>(x, cb, scc, flags, out_fidx);
    quant_kernel      <<<2048, 256, 0, stream>>>(x, cb, out_fidx, out, partial);
    loss_kernel       <<<1, 256, 0, stream>>>(partial, 2048, out_loss);
}

// Round 6
// 310.682 us; speedup vs baseline: 2.5907x; 1.4287x over previous
//
#include <hip/hip_runtime.h>

#define NUM_TAG 1024
#define TAG_DIM 128
#define NROWS   131072      // B*W = 128*1024
#define FLAG_M  1.25e-4f    // flag margin: >> 2*delta + np rounding windows
#define RPG     8           // rows per group in exact_fix

typedef __attribute__((ext_vector_type(8))) short short8;
typedef __attribute__((ext_vector_type(4))) float f32x4;

// Exact 2-way bf16 split: x = h + m + (residual < 2^-16 |x|), h/m bf16-exact.
__device__ inline void split2(float xv, unsigned short& h, unsigned short& m) {
    unsigned xb = __float_as_uint(xv);
    unsigned hb = xb & 0xFFFF0000u;
    float r1 = xv - __uint_as_float(hb);        // Sterbenz-exact
    unsigned mb = __float_as_uint(r1) & 0xFFFF0000u;
    h = (unsigned short)(hb >> 16);
    m = (unsigned short)(mb >> 16);
}

// -------- scc[k] = ||cb_k||^2 (round-1 sequential order, bit-identical) --------
__global__ __launch_bounds__(256) void prep_scc_kernel(
    const float* __restrict__ cb, float* __restrict__ scc)
{
    int k = blockIdx.x * 256 + threadIdx.x;
    if (k >= NUM_TAG) return;
    const float4* row = reinterpret_cast<const float4*>(cb) + k * (TAG_DIM / 4);
    float s = 0.f;
#pragma unroll
    for (int i = 0; i < TAG_DIM / 4; ++i) {
        float4 v = row[i];
        s += v.x * v.x; s += v.y * v.y; s += v.z * v.z; s += v.w * v.w;
    }
    scc[k] = s;
}

// -------- split codebook in MFMA-B-fragment-linear order --------
// Chunk = 64 codes: 2 arrays (h,m) x 16 (s,c) x 64 lanes x 8 elems = 16384 ushorts.
__global__ __launch_bounds__(256) void prep_frag_kernel(
    const float* __restrict__ cb, unsigned short* __restrict__ cbf)
{
    int t = blockIdx.x * 256 + threadIdx.x;
    int l  = t & 63;
    int c  = (t >> 6) & 3;
    int s  = (t >> 8) & 3;
    int ch = t >> 10;
    int k  = ch * 64 + c * 16 + (l & 15);
    int d0 = s * 32 + (l >> 4) * 8;
    const float4* xp = reinterpret_cast<const float4*>(cb) + k * 32 + (d0 >> 2);
    float4 v0 = xp[0], v1 = xp[1];
    float xv[8] = {v0.x, v0.y, v0.z, v0.w, v1.x, v1.y, v1.z, v1.w};
    short8 hh, mm;
#pragma unroll
    for (int e = 0; e < 8; ++e) {
        unsigned short h, m;
        split2(xv[e], h, m);
        hh[e] = (short)h; mm[e] = (short)m;
    }
    long baseh = (long)ch * 16384 + ((0 * 16 + s * 4 + c) * 64 + l) * 8;
    long basem = (long)ch * 16384 + ((1 * 16 + s * 4 + c) * 64 + l) * 8;
    *reinterpret_cast<short8*>(cbf + baseh) = hh;
    *reinterpret_cast<short8*>(cbf + basem) = mm;
}

// -------- pass A: split-bf16 MFMA scores + top-2 + near-tie flagging --------
// (unchanged from round 5 — verified absmax 0.0)
__global__ __launch_bounds__(512, 2) void argmin_mfma_kernel(
    const float* __restrict__ x,
    const unsigned short* __restrict__ cbf,
    const float* __restrict__ scc,
    float* __restrict__ fidx_out, int* __restrict__ flag_out)
{
    __shared__ __align__(16) unsigned short lds[2][16384];   // 2 x 32 KB

    const int tid = threadIdx.x;
    const int w   = tid >> 6;
    const int l   = tid & 63;
    const int l15 = l & 15;
    const int l4  = l >> 4;
    const int row0 = blockIdx.x * 256 + w * 32;

    short8 Ah[2][4], Am[2][4];
#pragma unroll
    for (int rf = 0; rf < 2; ++rf) {
        const float4* xp = reinterpret_cast<const float4*>(x) +
                           (long)(row0 + rf * 16 + l15) * 32 + l4 * 2;
#pragma unroll
        for (int s = 0; s < 4; ++s) {
            float4 v0 = xp[s * 8];
            float4 v1 = xp[s * 8 + 1];
            float xv[8] = {v0.x, v0.y, v0.z, v0.w, v1.x, v1.y, v1.z, v1.w};
#pragma unroll
            for (int e = 0; e < 8; ++e) {
                unsigned short h, m;
                split2(xv[e], h, m);
                Ah[rf][s][e] = (short)h;
                Am[rf][s][e] = (short)m;
            }
        }
    }

    float m1[2][4], m2[2][4]; int i1[2][4];
#pragma unroll
    for (int rf = 0; rf < 2; ++rf)
#pragma unroll
        for (int r = 0; r < 4; ++r) { m1[rf][r] = 3.4e38f; m2[rf][r] = 3.4e38f; i1[rf][r] = 0; }

    const float4* gsrc = reinterpret_cast<const float4*>(cbf);  // chunk = 2048 float4

    {
        float4 st[4];
#pragma unroll
        for (int i = 0; i < 4; ++i) st[i] = gsrc[i * 512 + tid];
#pragma unroll
        for (int i = 0; i < 4; ++i)
            reinterpret_cast<float4*>(&lds[0][0])[i * 512 + tid] = st[i];
    }
    __syncthreads();

    for (int ch = 0; ch < 16; ++ch) {
        const int b = ch & 1;
        float4 st[4];
        if (ch < 15) {
#pragma unroll
            for (int i = 0; i < 4; ++i)
                st[i] = gsrc[(ch + 1) * 2048 + i * 512 + tid];
        }

        const int col0 = ch << 6;
        f32x4 acc[2][4];
#pragma unroll
        for (int rf = 0; rf < 2; ++rf)
#pragma unroll
            for (int c = 0; c < 4; ++c) acc[rf][c] = (f32x4)0.f;

#pragma unroll
        for (int s = 0; s < 4; ++s) {
#pragma unroll
            for (int c = 0; c < 4; ++c) {
                const short8 Bh = *reinterpret_cast<const short8*>(
                    &lds[b][((0 * 16 + s * 4 + c) * 64 + l) * 8]);
                const short8 Bm = *reinterpret_cast<const short8*>(
                    &lds[b][((1 * 16 + s * 4 + c) * 64 + l) * 8]);
#pragma unroll
                for (int rf = 0; rf < 2; ++rf) {
                    acc[rf][c] = __builtin_amdgcn_mfma_f32_16x16x32_bf16(Ah[rf][s], Bm, acc[rf][c], 0, 0, 0);
                    acc[rf][c] = __builtin_amdgcn_mfma_f32_16x16x32_bf16(Am[rf][s], Bh, acc[rf][c], 0, 0, 0);
                    acc[rf][c] = __builtin_amdgcn_mfma_f32_16x16x32_bf16(Ah[rf][s], Bh, acc[rf][c], 0, 0, 0);
                }
            }
        }

#pragma unroll
        for (int c = 0; c < 4; ++c) {
            const int k = col0 + c * 16 + l15;
            const float sccv = scc[k];
#pragma unroll
            for (int rf = 0; rf < 2; ++rf)
#pragma unroll
                for (int r = 0; r < 4; ++r) {
                    float score = sccv - 2.0f * acc[rf][c][r];
                    if (score < m1[rf][r]) {
                        m2[rf][r] = m1[rf][r]; m1[rf][r] = score; i1[rf][r] = k;
                    } else if (score < m2[rf][r]) {
                        m2[rf][r] = score;
                    }
                }
        }

        __syncthreads();
        if (ch < 15) {
#pragma unroll
            for (int i = 0; i < 4; ++i)
                reinterpret_cast<float4*>(&lds[b ^ 1][0])[i * 512 + tid] = st[i];
        }
        __syncthreads();
    }

#pragma unroll
    for (int rf = 0; rf < 2; ++rf)
#pragma unroll
        for (int r = 0; r < 4; ++r) {
            float v1 = m1[rf][r], v2 = m2[rf][r]; int ii = i1[rf][r];
#pragma unroll
            for (int mk = 1; mk < 16; mk <<= 1) {
                float o1 = __shfl_xor(v1, mk, 64);
                float o2 = __shfl_xor(v2, mk, 64);
                int   oi = __shfl_xor(ii, mk, 64);
                float n2 = fminf(fminf(v2, o2), fmaxf(v1, o1));
                if (o1 < v1 || (o1 == v1 && oi < ii)) { v1 = o1; ii = oi; }
                v2 = n2;
            }
            if (l15 == 0) {
                int row = row0 + rf * 16 + l4 * 4 + r;
                fidx_out[row] = (float)ii;
                flag_out[row] = (v2 - v1 <= FLAG_M) ? 1 : 0;
            }
        }
}

// -------- compact flagged rows into a dense list --------
__global__ __launch_bounds__(64) void zero_count_kernel(int* __restrict__ count) {
    if (threadIdx.x == 0) count[0] = 0;
}

__global__ __launch_bounds__(256) void compact_kernel(
    const int* __restrict__ flag, int* __restrict__ list, int* __restrict__ count)
{
    int i = blockIdx.x * 256 + threadIdx.x;
    int f = flag[i];
    unsigned long long mask = __ballot(f != 0);
    int lane = threadIdx.x & 63;
    int base = 0;
    if (lane == 0 && mask) base = atomicAdd(count, __popcll(mask));
    base = __shfl(base, 0, 64);
    if (f) {
        int pos = base + (int)__popcll(mask & ((1ULL << lane) - 1ULL));
        list[pos] = i;
    }
}

// -------- pass B: exact rescore, RPG rows per block-group --------
// Per (row,code): sequential fp32 fmac dot (i ascending, x/y/z/w), dist =
// (sxx+scc) - 2*dot, tie -> lowest k. Bit-identical to the round-1 recipe.
__global__ __launch_bounds__(256) void exact_fix_kernel(
    const float* __restrict__ x, const float* __restrict__ cb,
    const float* __restrict__ scc, const int* __restrict__ list,
    const int* __restrict__ count, float* __restrict__ fidx_out)
{
    __shared__ float4 Xs[RPG][32];
    __shared__ float  sxxs[RPG];
    __shared__ float  wrv[RPG][4];
    __shared__ int    wri[RPG][4];
    __shared__ int    rows_s[RPG];

    const int tid  = threadIdx.x;
    const int lane = tid & 63;
    const int wv   = tid >> 6;
    const int nflag = count[0];
    const int ngroups = (nflag + RPG - 1) / RPG;

    for (int g = blockIdx.x; g < ngroups; g += gridDim.x) {
        const int nr = min(RPG, nflag - g * RPG);
        if (tid < RPG)
            rows_s[tid] = list[g * RPG + min(tid, nr - 1)];   // dup last for tail
        __syncthreads();
        {   // stage 8 rows x 32 float4
            int r = tid >> 5, i = tid & 31;
            Xs[r][i] = reinterpret_cast<const float4*>(x)[(long)rows_s[r] * 32 + i];
        }
        __syncthreads();
        if (tid < RPG) {   // per-row sxx, sequential order
            float s = 0.f;
            for (int i = 0; i < 32; ++i) {
                float4 v = Xs[tid][i];
                s += v.x * v.x; s += v.y * v.y; s += v.z * v.z; s += v.w * v.w;
            }
            sxxs[tid] = s;
        }
        __syncthreads();

        // 4 codes per thread: k = tid*4+j (in-thread ascending)
        float acc[RPG][4];
#pragma unroll
        for (int r = 0; r < RPG; ++r)
#pragma unroll
            for (int j = 0; j < 4; ++j) acc[r][j] = 0.f;

        const float4* crow = reinterpret_cast<const float4*>(cb) + (tid * 4) * 32;
        for (int i = 0; i < 32; ++i) {
            float4 xv[RPG];
#pragma unroll
            for (int r = 0; r < RPG; ++r) xv[r] = Xs[r][i];
#pragma unroll
            for (int j = 0; j < 4; ++j) {
                float4 c = crow[j * 32 + i];
#pragma unroll
                for (int r = 0; r < RPG; ++r) {
                    acc[r][j] += xv[r].x * c.x;
                    acc[r][j] += xv[r].y * c.y;
                    acc[r][j] += xv[r].z * c.z;
                    acc[r][j] += xv[r].w * c.w;
                }
            }
        }

#pragma unroll
        for (int r = 0; r < RPG; ++r) {
            float bv = 3.4e38f; int bi = 0;
            const float sxxv = sxxs[r];
#pragma unroll
            for (int j = 0; j < 4; ++j) {
                int k = tid * 4 + j;
                float s1 = sxxv + scc[k];          // np: (sxx + scc)
                float dist = s1 - 2.0f * acc[r][j]; // np: ... - 2*dot
                if (dist < bv) { bv = dist; bi = k; }
            }
            // wave reduce (tie -> lowest k)
#pragma unroll
            for (int mk = 1; mk < 64; mk <<= 1) {
                float ov = __shfl_xor(bv, mk, 64);
                int   oi = __shfl_xor(bi, mk, 64);
                if (ov < bv || (ov == bv && oi < bi)) { bv = ov; bi = oi; }
            }
            if (lane == 0) { wrv[r][wv] = bv; wri[r][wv] = bi; }
        }
        __syncthreads();
        if (tid < RPG && tid < nr) {
            float bv = wrv[tid][0]; int bi = wri[tid][0];
#pragma unroll
            for (int e = 1; e < 4; ++e) {
                float v = wrv[tid][e]; int oi = wri[tid][e];
                if (v < bv || (v == bv && oi < bi)) { bv = v; bi = oi; }
            }
            fidx_out[rows_s[tid]] = (float)bi;
        }
        __syncthreads();
    }
}

// -------- phase 2: gather + STE output + loss partials --------
__global__ __launch_bounds__(256) void quant_kernel(
    const float* __restrict__ x, const float* __restrict__ cb,
    const float* __restrict__ fidx, float* __restrict__ out,
    double* __restrict__ partial)
{
    const int N4 = NROWS * (TAG_DIM / 4);
    double s = 0.0;
    for (int i = blockIdx.x * blockDim.x + threadIdx.x; i < N4; i += gridDim.x * blockDim.x) {
        int n = i >> 5;
        int d4 = i & 31;
        int k = (int)fidx[n];
        float4 xv = reinterpret_cast<const float4*>(x)[i];
        float4 qv = reinterpret_cast<const float4*>(cb)[k * 32 + d4];
        float dx = qv.x - xv.x, dy = qv.y - xv.y, dz = qv.z - xv.z, dw = qv.w - xv.w;
        float4 o;
        o.x = xv.x + dx; o.y = xv.y + dy; o.z = xv.z + dz; o.w = xv.w + dw;
        reinterpret_cast<float4*>(out)[i] = o;
        s += (double)dx * dx; s += (double)dy * dy; s += (double)dz * dz; s += (double)dw * dw;
    }
    __shared__ double sd[256];
    sd[threadIdx.x] = s;
    __syncthreads();
    for (int off = 128; off > 0; off >>= 1) {
        if (threadIdx.x < (unsigned)off) sd[threadIdx.x] += sd[threadIdx.x + off];
        __syncthreads();
    }
    if (threadIdx.x == 0) partial[blockIdx.x] = sd[0];
}

__global__ __launch_bounds__(256) void loss_kernel(
    const double* __restrict__ partial, int n, float* __restrict__ out_loss)
{
    __shared__ double sd[256];
    double s = 0.0;
    for (int i = threadIdx.x; i < n; i += 256) s += partial[i];
    sd[threadIdx.x] = s;
    __syncthreads();
    for (int off = 128; off > 0; off >>= 1) {
        if (threadIdx.x < (unsigned)off) sd[threadIdx.x] += sd[threadIdx.x + off];
        __syncthreads();
    }
    if (threadIdx.x == 0) {
        double mean = sd[0] / (double)((long long)NROWS * TAG_DIM);
        out_loss[0] = (float)(mean + 0.25 * mean);
    }
}

extern "C" void kernel_launch(void* const* d_in, const int* in_sizes, int n_in,
                              void* d_out, int out_size, void* d_ws, size_t ws_size,
                              hipStream_t stream) {
    const float* x  = (const float*)d_in[0];   // [131072][128]
    const float* cb = (const float*)d_in[1];   // [1024][128]
    float* out      = (float*)d_out;
    float* out_loss = out + (long)NROWS * TAG_DIM;
    float* out_fidx = out_loss + 1;            // 131072 indices as f32

    // ws layout (~1.6 MB): scc | cbf | flags | list | count | partial
    char* wsb = (char*)d_ws;
    float*          scc     = (float*)(wsb);                     // 4 KB
    unsigned short* cbf     = (unsigned short*)(wsb + 4096);     // 512 KB
    int*            flags   = (int*)(wsb + 528384);              // 512 KB
    int*            list    = (int*)(wsb + 1052672);             // 512 KB
    int*            count   = (int*)(wsb + 1576960);             // 64 B
    double*         partial = (double*)(wsb + 1577024);          // 16 KB

    prep_scc_kernel   <<<4, 256, 0, stream>>>(cb, scc);
    prep_frag_kernel  <<<64, 256, 0, stream>>>(cb, cbf);
    zero_count_kernel <<<1, 64, 0, stream>>>(count);
    argmin_mfma_kernel<<<NROWS / 256, 512, 0, stream>>>(x, cbf, scc, out_fidx, flags);
    compact_kernel    <<<NROWS / 256, 256, 0, stream>>>(flags, list, count);
    exact_fix_kernel  <<<512, 256, 0, stream>>>(x, cb, scc, list, count, out_fidx);
    quant_kernel      <<<2048, 256, 0, stream>>>(x, cb, out_fidx, out, partial);
    loss_kernel       <<<1, 256, 0, stream>>>(partial, 2048, out_loss);
}

// Round 7
// 268.734 us; speedup vs baseline: 2.9951x; 1.1561x over previous
//
#include <hip/hip_runtime.h>

#define NUM_TAG 1024
#define TAG_DIM 128
#define NROWS   131072      // B*W = 128*1024
#define FLAG_M  1.25e-4f    // flag margin: >> 2*delta + np rounding windows
#define RPG     8           // rows per group in exact_fix

typedef __attribute__((ext_vector_type(8))) short short8;
typedef __attribute__((ext_vector_type(4))) float f32x4;

// Exact 2-way bf16 split: x = h + m + (residual < 2^-16 |x|), h/m bf16-exact.
__device__ inline void split2(float xv, unsigned short& h, unsigned short& m) {
    unsigned xb = __float_as_uint(xv);
    unsigned hb = xb & 0xFFFF0000u;
    float r1 = xv - __uint_as_float(hb);        // Sterbenz-exact
    unsigned mb = __float_as_uint(r1) & 0xFFFF0000u;
    h = (unsigned short)(hb >> 16);
    m = (unsigned short)(mb >> 16);
}

// async global->LDS, 16B per lane (linear LDS dest = wave-uniform base + lane*16)
__device__ inline void gld_lds16(const void* g, void* l) {
    __builtin_amdgcn_global_load_lds(
        (const __attribute__((address_space(1))) void*)g,
        (__attribute__((address_space(3))) void*)l, 16, 0, 0);
}

// -------- scc[k] = ||cb_k||^2 (round-1 sequential order, bit-identical) --------
__global__ __launch_bounds__(256) void prep_scc_kernel(
    const float* __restrict__ cb, float* __restrict__ scc)
{
    int k = blockIdx.x * 256 + threadIdx.x;
    if (k >= NUM_TAG) return;
    const float4* row = reinterpret_cast<const float4*>(cb) + k * (TAG_DIM / 4);
    float s = 0.f;
#pragma unroll
    for (int i = 0; i < TAG_DIM / 4; ++i) {
        float4 v = row[i];
        s += v.x * v.x; s += v.y * v.y; s += v.z * v.z; s += v.w * v.w;
    }
    scc[k] = s;
}

// -------- split codebook in MFMA-B-fragment-linear order --------
// Chunk = 32 codes: 2 arrays (h,m) x 4 s x 2 c x 64 lanes x 8 elems
//       = 8192 ushorts = 16 KB. 32 chunks total.
// cbf[ch*8192 + ((arr*8 + s*2 + c)*64 + l)*8 + e]
//   = split(cb[ch*32 + c*16 + (l&15)][s*32 + (l>>4)*8 + e])
__global__ __launch_bounds__(256) void prep_frag_kernel(
    const float* __restrict__ cb, unsigned short* __restrict__ cbf)
{
    int t = blockIdx.x * 256 + threadIdx.x;
    int l  = t & 63;
    int c  = (t >> 6) & 1;
    int s  = (t >> 7) & 3;
    int ch = t >> 9;
    int k  = ch * 32 + c * 16 + (l & 15);
    int d0 = s * 32 + (l >> 4) * 8;
    const float4* xp = reinterpret_cast<const float4*>(cb) + k * 32 + (d0 >> 2);
    float4 v0 = xp[0], v1 = xp[1];
    float xv[8] = {v0.x, v0.y, v0.z, v0.w, v1.x, v1.y, v1.z, v1.w};
    short8 hh, mm;
#pragma unroll
    for (int e = 0; e < 8; ++e) {
        unsigned short h, m;
        split2(xv[e], h, m);
        hh[e] = (short)h; mm[e] = (short)m;
    }
    long baseh = (long)ch * 8192 + (((0 * 8) + s * 2 + c) * 64 + l) * 8;
    long basem = (long)ch * 8192 + (((1 * 8) + s * 2 + c) * 64 + l) * 8;
    *reinterpret_cast<short8*>(cbf + baseh) = hh;
    *reinterpret_cast<short8*>(cbf + basem) = mm;
}

// -------- pass A: split-bf16 MFMA scores + top-2 + near-tie flagging --------
// 256 threads = 4 waves, 128 rows/block (32/wave), 1024 blocks (~4/CU).
// B staged via global_load_lds double buffer, ONE barrier per chunk.
// Per-code scores bit-identical to rounds 3-6 (same 3-MFMA x 4-s sequence
// from acc=0, fold visits k ascending per lane, tie -> lowest k).
__global__ __launch_bounds__(256, 3) void argmin_mfma_kernel(
    const float* __restrict__ x,
    const unsigned short* __restrict__ cbf,
    const float* __restrict__ scc,
    float* __restrict__ fidx_out, int* __restrict__ flag_out)
{
    __shared__ __align__(16) unsigned short lds[2][8192];   // 2 x 16 KB

    const int tid = threadIdx.x;
    const int w   = tid >> 6;
    const int l   = tid & 63;
    const int l15 = l & 15;
    const int l4  = l >> 4;
    const int row0 = blockIdx.x * 128 + w * 32;

    // ---- A fragments: lane holds row l15 (+16*rf), k-slice l4*8+e, step s ----
    short8 Ah[2][4], Am[2][4];
#pragma unroll
    for (int rf = 0; rf < 2; ++rf) {
        const float4* xp = reinterpret_cast<const float4*>(x) +
                           (long)(row0 + rf * 16 + l15) * 32 + l4 * 2;
#pragma unroll
        for (int s = 0; s < 4; ++s) {
            float4 v0 = xp[s * 8];
            float4 v1 = xp[s * 8 + 1];
            float xv[8] = {v0.x, v0.y, v0.z, v0.w, v1.x, v1.y, v1.z, v1.w};
#pragma unroll
            for (int e = 0; e < 8; ++e) {
                unsigned short h, m;
                split2(xv[e], h, m);
                Ah[rf][s][e] = (short)h;
                Am[rf][s][e] = (short)m;
            }
        }
    }

    float m1[2][4], m2[2][4]; int i1[2][4];
#pragma unroll
    for (int rf = 0; rf < 2; ++rf)
#pragma unroll
        for (int r = 0; r < 4; ++r) { m1[rf][r] = 3.4e38f; m2[rf][r] = 3.4e38f; i1[rf][r] = 0; }

    const float4* gsrc = reinterpret_cast<const float4*>(cbf);  // chunk = 1024 float4

    // ---- prologue: stage chunk 0 into lds[0] ----
#pragma unroll
    for (int i = 0; i < 4; ++i)
        gld_lds16(gsrc + i * 256 + tid, (void*)&lds[0][(i * 256 + tid) * 8]);
    __syncthreads();   // implies vmcnt(0)

    for (int ch = 0; ch < 32; ++ch) {
        const int b = ch & 1;
        // issue next-chunk loads into the other buffer (latency hides under MFMA)
        if (ch < 31) {
            const float4* gp = gsrc + (ch + 1) * 1024 + tid;
#pragma unroll
            for (int i = 0; i < 4; ++i)
                gld_lds16(gp + i * 256, (void*)&lds[b ^ 1][(i * 256 + tid) * 8]);
        }

        const int col0 = ch << 5;
        f32x4 acc[2][2];
#pragma unroll
        for (int rf = 0; rf < 2; ++rf)
#pragma unroll
            for (int c = 0; c < 2; ++c) acc[rf][c] = (f32x4)0.f;

#pragma unroll
        for (int s = 0; s < 4; ++s) {
#pragma unroll
            for (int c = 0; c < 2; ++c) {
                const short8 Bh = *reinterpret_cast<const short8*>(
                    &lds[b][(((0 * 8) + s * 2 + c) * 64 + l) * 8]);
                const short8 Bm = *reinterpret_cast<const short8*>(
                    &lds[b][(((1 * 8) + s * 2 + c) * 64 + l) * 8]);
#pragma unroll
                for (int rf = 0; rf < 2; ++rf) {
                    acc[rf][c] = __builtin_amdgcn_mfma_f32_16x16x32_bf16(Ah[rf][s], Bm, acc[rf][c], 0, 0, 0);
                    acc[rf][c] = __builtin_amdgcn_mfma_f32_16x16x32_bf16(Am[rf][s], Bh, acc[rf][c], 0, 0, 0);
                    acc[rf][c] = __builtin_amdgcn_mfma_f32_16x16x32_bf16(Ah[rf][s], Bh, acc[rf][c], 0, 0, 0);
                }
            }
        }

        // fold into running top-2 per output row (k ascending per lane)
#pragma unroll
        for (int c = 0; c < 2; ++c) {
            const int k = col0 + c * 16 + l15;
            const float sccv = scc[k];
#pragma unroll
            for (int rf = 0; rf < 2; ++rf)
#pragma unroll
                for (int r = 0; r < 4; ++r) {
                    float score = sccv - 2.0f * acc[rf][c][r];
                    if (score < m1[rf][r]) {
                        m2[rf][r] = m1[rf][r]; m1[rf][r] = score; i1[rf][r] = k;
                    } else if (score < m2[rf][r]) {
                        m2[rf][r] = score;
                    }
                }
        }

        __syncthreads();   // drains vmcnt(0): staged chunk ready, readers of b^1 done
    }

    // ---- cross-lane top-2 merge within each 16-lane col group ----
#pragma unroll
    for (int rf = 0; rf < 2; ++rf)
#pragma unroll
        for (int r = 0; r < 4; ++r) {
            float v1 = m1[rf][r], v2 = m2[rf][r]; int ii = i1[rf][r];
#pragma unroll
            for (int mk = 1; mk < 16; mk <<= 1) {
                float o1 = __shfl_xor(v1, mk, 64);
                float o2 = __shfl_xor(v2, mk, 64);
                int   oi = __shfl_xor(ii, mk, 64);
                float n2 = fminf(fminf(v2, o2), fmaxf(v1, o1));  // global 2nd-min
                if (o1 < v1 || (o1 == v1 && oi < ii)) { v1 = o1; ii = oi; }
                v2 = n2;
            }
            if (l15 == 0) {
                int row = row0 + rf * 16 + l4 * 4 + r;
                fidx_out[row] = (float)ii;
                flag_out[row] = (v2 - v1 <= FLAG_M) ? 1 : 0;
            }
        }
}

// -------- compact flagged rows into a dense list --------
__global__ __launch_bounds__(64) void zero_count_kernel(int* __restrict__ count) {
    if (threadIdx.x == 0) count[0] = 0;
}

__global__ __launch_bounds__(256) void compact_kernel(
    const int* __restrict__ flag, int* __restrict__ list, int* __restrict__ count)
{
    int i = blockIdx.x * 256 + threadIdx.x;
    int f = flag[i];
    unsigned long long mask = __ballot(f != 0);
    int lane = threadIdx.x & 63;
    int base = 0;
    if (lane == 0 && mask) base = atomicAdd(count, __popcll(mask));
    base = __shfl(base, 0, 64);
    if (f) {
        int pos = base + (int)__popcll(mask & ((1ULL << lane) - 1ULL));
        list[pos] = i;
    }
}

// -------- pass B: exact rescore, RPG rows per block-group --------
// Per (row,code): sequential fp32 fmac dot (i ascending, x/y/z/w), dist =
// (sxx+scc) - 2*dot, tie -> lowest k. Bit-identical to the round-1 recipe.
__global__ __launch_bounds__(256) void exact_fix_kernel(
    const float* __restrict__ x, const float* __restrict__ cb,
    const float* __restrict__ scc, const int* __restrict__ list,
    const int* __restrict__ count, float* __restrict__ fidx_out)
{
    __shared__ float4 Xs[RPG][32];
    __shared__ float  sxxs[RPG];
    __shared__ float  wrv[RPG][4];
    __shared__ int    wri[RPG][4];
    __shared__ int    rows_s[RPG];

    const int tid  = threadIdx.x;
    const int lane = tid & 63;
    const int wv   = tid >> 6;
    const int nflag = count[0];
    const int ngroups = (nflag + RPG - 1) / RPG;

    for (int g = blockIdx.x; g < ngroups; g += gridDim.x) {
        const int nr = min(RPG, nflag - g * RPG);
        if (tid < RPG)
            rows_s[tid] = list[g * RPG + min(tid, nr - 1)];   // dup last for tail
        __syncthreads();
        {   // stage 8 rows x 32 float4
            int r = tid >> 5, i = tid & 31;
            Xs[r][i] = reinterpret_cast<const float4*>(x)[(long)rows_s[r] * 32 + i];
        }
        __syncthreads();
        if (tid < RPG) {   // per-row sxx, sequential order
            float s = 0.f;
            for (int i = 0; i < 32; ++i) {
                float4 v = Xs[tid][i];
                s += v.x * v.x; s += v.y * v.y; s += v.z * v.z; s += v.w * v.w;
            }
            sxxs[tid] = s;
        }
        __syncthreads();

        // 4 codes per thread: k = tid*4+j (in-thread ascending)
        float acc[RPG][4];
#pragma unroll
        for (int r = 0; r < RPG; ++r)
#pragma unroll
            for (int j = 0; j < 4; ++j) acc[r][j] = 0.f;

        const float4* crow = reinterpret_cast<const float4*>(cb) + (tid * 4) * 32;
        for (int i = 0; i < 32; ++i) {
            float4 xv[RPG];
#pragma unroll
            for (int r = 0; r < RPG; ++r) xv[r] = Xs[r][i];
#pragma unroll
            for (int j = 0; j < 4; ++j) {
                float4 c = crow[j * 32 + i];
#pragma unroll
                for (int r = 0; r < RPG; ++r) {
                    acc[r][j] += xv[r].x * c.x;
                    acc[r][j] += xv[r].y * c.y;
                    acc[r][j] += xv[r].z * c.z;
                    acc[r][j] += xv[r].w * c.w;
                }
            }
        }

#pragma unroll
        for (int r = 0; r < RPG; ++r) {
            float bv = 3.4e38f; int bi = 0;
            const float sxxv = sxxs[r];
#pragma unroll
            for (int j = 0; j < 4; ++j) {
                int k = tid * 4 + j;
                float s1 = sxxv + scc[k];          // np: (sxx + scc)
                float dist = s1 - 2.0f * acc[r][j]; // np: ... - 2*dot
                if (dist < bv) { bv = dist; bi = k; }
            }
            // wave reduce (tie -> lowest k)
#pragma unroll
            for (int mk = 1; mk < 64; mk <<= 1) {
                float ov = __shfl_xor(bv, mk, 64);
                int   oi = __shfl_xor(bi, mk, 64);
                if (ov < bv || (ov == bv && oi < bi)) { bv = ov; bi = oi; }
            }
            if (lane == 0) { wrv[r][wv] = bv; wri[r][wv] = bi; }
        }
        __syncthreads();
        if (tid < RPG && tid < nr) {
            float bv = wrv[tid][0]; int bi = wri[tid][0];
#pragma unroll
            for (int e = 1; e < 4; ++e) {
                float v = wrv[tid][e]; int oi = wri[tid][e];
                if (v < bv || (v == bv && oi < bi)) { bv = v; bi = oi; }
            }
            fidx_out[rows_s[tid]] = (float)bi;
        }
        __syncthreads();
    }
}

// -------- phase 2: gather + STE output + loss partials --------
__global__ __launch_bounds__(256) void quant_kernel(
    const float* __restrict__ x, const float* __restrict__ cb,
    const float* __restrict__ fidx, float* __restrict__ out,
    double* __restrict__ partial)
{
    const int N4 = NROWS * (TAG_DIM / 4);
    double s = 0.0;
    for (int i = blockIdx.x * blockDim.x + threadIdx.x; i < N4; i += gridDim.x * blockDim.x) {
        int n = i >> 5;
        int d4 = i & 31;
        int k = (int)fidx[n];
        float4 xv = reinterpret_cast<const float4*>(x)[i];
        float4 qv = reinterpret_cast<const float4*>(cb)[k * 32 + d4];
        float dx = qv.x - xv.x, dy = qv.y - xv.y, dz = qv.z - xv.z, dw = qv.w - xv.w;
        float4 o;
        o.x = xv.x + dx; o.y = xv.y + dy; o.z = xv.z + dz; o.w = xv.w + dw;
        reinterpret_cast<float4*>(out)[i] = o;
        s += (double)dx * dx; s += (double)dy * dy; s += (double)dz * dz; s += (double)dw * dw;
    }
    __shared__ double sd[256];
    sd[threadIdx.x] = s;
    __syncthreads();
    for (int off = 128; off > 0; off >>= 1) {
        if (threadIdx.x < (unsigned)off) sd[threadIdx.x] += sd[threadIdx.x + off];
        __syncthreads();
    }
    if (threadIdx.x == 0) partial[blockIdx.x] = sd[0];
}

__global__ __launch_bounds__(256) void loss_kernel(
    const double* __restrict__ partial, int n, float* __restrict__ out_loss)
{
    __shared__ double sd[256];
    double s = 0.0;
    for (int i = threadIdx.x; i < n; i += 256) s += partial[i];
    sd[threadIdx.x] = s;
    __syncthreads();
    for (int off = 128; off > 0; off >>= 1) {
        if (threadIdx.x < (unsigned)off) sd[threadIdx.x] += sd[threadIdx.x + off];
        __syncthreads();
    }
    if (threadIdx.x == 0) {
        double mean = sd[0] / (double)((long long)NROWS * TAG_DIM);
        out_loss[0] = (float)(mean + 0.25 * mean);
    }
}

extern "C" void kernel_launch(void* const* d_in, const int* in_sizes, int n_in,
                              void* d_out, int out_size, void* d_ws, size_t ws_size,
                              hipStream_t stream) {
    const float* x  = (const float*)d_in[0];   // [131072][128]
    const float* cb = (const float*)d_in[1];   // [1024][128]
    float* out      = (float*)d_out;
    float* out_loss = out + (long)NROWS * TAG_DIM;
    float* out_fidx = out_loss + 1;            // 131072 indices as f32

    // ws layout (~1.6 MB): scc | cbf | flags | list | count | partial
    char* wsb = (char*)d_ws;
    float*          scc     = (float*)(wsb);                     // 4 KB
    unsigned short* cbf     = (unsigned short*)(wsb + 4096);     // 512 KB
    int*            flags   = (int*)(wsb + 528384);              // 512 KB
    int*            list    = (int*)(wsb + 1052672);             // 512 KB
    int*            count   = (int*)(wsb + 1576960);             // 64 B
    double*         partial = (double*)(wsb + 1577024);          // 16 KB

    prep_scc_kernel   <<<4, 256, 0, stream>>>(cb, scc);
    prep_frag_kernel  <<<64, 256, 0, stream>>>(cb, cbf);
    zero_count_kernel <<<1, 64, 0, stream>>>(count);
    argmin_mfma_kernel<<<NROWS / 128, 256, 0, stream>>>(x, cbf, scc, out_fidx, flags);
    compact_kernel    <<<NROWS / 256, 256, 0, stream>>>(flags, list, count);
    exact_fix_kernel  <<<512, 256, 0, stream>>>(x, cb, scc, list, count, out_fidx);
    quant_kernel      <<<2048, 256, 0, stream>>>(x, cb, out_fidx, out, partial);
    loss_kernel       <<<1, 256, 0, stream>>>(partial, 2048, out_loss);
}